// Round 7
// baseline (164.721 us; speedup 1.0000x reference)
//
#include <hip/hip_runtime.h>

#define NB 8
#define NH 512
#define NW 640
#define NHW (NH*NW)
#define NBHW (NB*NHW)
#define TOPK 512
#define CAP 40960
#define PAD 8
#define CNT_STRIDE 64   // one counter per 256B cacheline
#define NBUCKET 32
#define GCAP 4096       // topk gather capacity (32 KB LDS)
#define ALCAP (16 * TOPK * 25)   // affected-pixel list capacity: 8 img * 512 * 25 (exact bound)

// NMS tile geometry (block = 256 threads)
#define TW 64
#define TH 16

// Gaussian taps exp(-2 d^2); |d|>=3 taps are <=1.52e-8 -> negligible, radius 2 used
#define G0 1.0f
#define G1 0.1353352832366127f
#define G2 3.3546262790251185e-4f

__device__ __forceinline__ float bordered(const float* __restrict__ img, int b, int y, int x) {
  if (y < PAD || y >= NH - PAD || x < PAD || x >= NW - PAD) return 0.f;
  return img[b * NHW + y * NW + x];
}

// Monotone (weakly increasing in val) bucket index, fine-grained near 1.0.
__device__ __forceinline__ int vbucket(float val) {
  int d = 0x3F800000 - (int)__float_as_uint(val);
  if (d <= 0) return NBUCKET - 1;        // val >= 1.0
  int c = __clz(d);                       // 2..31
  return c > 30 ? 30 : c;
}

__device__ __forceinline__ void corner(const float* __restrict__ img, float cx, float cy,
                                       float wgt, float& acc, float& vacc) {
  float valid = (cx >= 0.f && cx <= (float)(NW - 1) && cy >= 0.f && cy <= (float)(NH - 1)) ? 1.f : 0.f;
  float xc = fminf(fmaxf(cx, 0.f), (float)(NW - 1));
  float yc = fminf(fmaxf(cy, 0.f), (float)(NH - 1));
  int xi = (int)xc, yi = (int)yc;
  float g = img[yi * NW + xi] * valid;
  acc += wgt * g;
  vacc += wgt * valid;
}

// Analytic visibility mask: does the warped sample at (gx,gy) touch any valid corner?
__device__ __forceinline__ float visv(float h0, float h1, float h2, float h3, float h4,
                                      float h5, float h6, float h7, float h8,
                                      int gx, int gy) {
  float xf = (float)gx, yf = (float)gy;
  float X = h0 * xf + h1 * yf + h2;
  float Y = h3 * xf + h4 * yf + h5;
  float Z = h6 * xf + h7 * yf + h8;
  float x2 = X / Z, y2 = Y / Z;
  float x0 = floorf(x2), y0 = floorf(y2);
  float x1 = x0 + 1.f, y1 = y0 + 1.f;
  float wa = (x1 - x2) * (y1 - y2);
  float wb = (x2 - x0) * (y1 - y2);
  float wc = (x1 - x2) * (y2 - y0);
  float wd = (x2 - x0) * (y2 - y0);
  float va = (x0 >= 0.f && x0 <= (float)(NW - 1) && y0 >= 0.f && y0 <= (float)(NH - 1)) ? 1.f : 0.f;
  float vb = (x1 >= 0.f && x1 <= (float)(NW - 1) && y0 >= 0.f && y0 <= (float)(NH - 1)) ? 1.f : 0.f;
  float vc = (x0 >= 0.f && x0 <= (float)(NW - 1) && y1 >= 0.f && y1 <= (float)(NH - 1)) ? 1.f : 0.f;
  float vd = (x1 >= 0.f && x1 <= (float)(NW - 1) && y1 >= 0.f && y1 <= (float)(NH - 1)) ? 1.f : 0.f;
  float vacc = wa * va; vacc += wb * vb; vacc += wc * vc; vacc += wd * vd;
  return (vacc > 0.f) ? 1.f : 0.f;
}

// Fused warp + border-filter + 5x5 separable NMS + bucket counts.
// src==0 blocks additionally accumulate the dense loss terms Sum(s1^2 * v), Sum(v)
// (s1 already in LDS; v analytic from homography -- no extra memory traffic).
__global__ void k_nms3(const float* __restrict__ score1, const float* __restrict__ score2,
                       const float* __restrict__ homo,
                       unsigned long long* __restrict__ lists, unsigned int* __restrict__ cbase,
                       unsigned long long* __restrict__ accum) {
  int bx = blockIdx.x, by = blockIdx.y;
  int src = blockIdx.z >> 3, b = blockIdx.z & 7;
  int tid = threadIdx.x;

  __shared__ float in[TH + 4][TW + 4];     // 20 x 68
  __shared__ float hmax[TH + 4][TW];       // 20 x 64
  __shared__ unsigned int s_cnt;
  __shared__ unsigned int s_base;
  __shared__ unsigned int s_bh[NBUCKET];
  __shared__ float shA[256];
  __shared__ unsigned int shI[256];

  if (tid == 0) s_cnt = 0;
  if (tid < NBUCKET) s_bh[tid] = 0;

  const float* hm = homo + b * 9;
  float h0 = hm[0], h1 = hm[1], h2 = hm[2];
  float h3 = hm[3], h4 = hm[4], h5 = hm[5];
  float h6 = hm[6], h7 = hm[7], h8 = hm[8];

  // Phase 1: stage tile (+2 halo) into LDS, border-filtered.
  for (int i = tid; i < (TH + 4) * (TW + 4); i += 256) {
    int r = i / (TW + 4), c = i % (TW + 4);
    int gy = by * TH + r - 2, gx = bx * TW + c - 2;
    float v = 0.f;
    if (src == 0) {
      v = bordered(score1, b, gy, gx);
    } else {
      bool inb = (gy >= PAD && gy < NH - PAD && gx >= PAD && gx < NW - PAD);
      if (inb) {
        float xf = (float)gx, yf = (float)gy;
        float X = h0 * xf + h1 * yf + h2;
        float Y = h3 * xf + h4 * yf + h5;
        float Z = h6 * xf + h7 * yf + h8;
        float x2 = X / Z, y2 = Y / Z;
        float x0 = floorf(x2), y0 = floorf(y2);
        float x1 = x0 + 1.f, y1 = y0 + 1.f;
        float wa = (x1 - x2) * (y1 - y2);
        float wb = (x2 - x0) * (y1 - y2);
        float wc = (x1 - x2) * (y2 - y0);
        float wd = (x2 - x0) * (y2 - y0);
        const float* img = score2 + b * NHW;
        float acc = 0.f, vacc = 0.f;
        corner(img, x0, y0, wa, acc, vacc);
        corner(img, x1, y0, wb, acc, vacc);
        corner(img, x0, y1, wc, acc, vacc);
        corner(img, x1, y1, wd, acc, vacc);
        v = acc;
      }
    }
    in[r][c] = v;
  }
  __syncthreads();

  // Phase 2: horizontal 5-max
  for (int i = tid; i < (TH + 4) * TW; i += 256) {
    int r = i / TW, c = i % TW;
    float m = fmaxf(fmaxf(fmaxf(in[r][c], in[r][c + 1]), fmaxf(in[r][c + 2], in[r][c + 3])),
                    in[r][c + 4]);
    hmax[r][c] = m;
  }
  __syncthreads();

  // Phase 3: vertical 5-max + survivor detection; src0 also dense loss terms
  int nsv = 0;
  float svals[4];
  unsigned int sidx[4];
  float tsum = 0.f;
  unsigned int vcnt = 0;
  #pragma unroll
  for (int it = 0; it < (TH * TW) / 256; ++it) {
    int i = it * 256 + tid;
    int r = i / TW, c = i % TW;
    int gy = by * TH + r, gx = bx * TW + c;
    float val = in[r + 2][c + 2];
    if (src == 0) {
      float v = visv(h0, h1, h2, h3, h4, h5, h6, h7, h8, gx, gy);
      tsum += val * val * v;
      vcnt += (v > 0.f) ? 1u : 0u;
    }
    if (val > 0.f) {   // NMS_THRESH = 0
      float m = fmaxf(fmaxf(fmaxf(hmax[r][c], hmax[r + 1][c]), fmaxf(hmax[r + 2][c], hmax[r + 3][c])),
                      hmax[r + 4][c]);
      if (m == val) {
        svals[nsv] = val;
        sidx[nsv] = (unsigned int)(gy * NW + gx);
        ++nsv;
      }
    }
  }

  // Phase 4: block-aggregated push + bucket counts
  unsigned int local = 0;
  if (nsv > 0) local = atomicAdd(&s_cnt, (unsigned int)nsv);
  for (int j = 0; j < nsv; ++j) atomicAdd(&s_bh[vbucket(svals[j])], 1u);
  __syncthreads();
  int li = src * NB + b;
  if (tid == 0 && s_cnt > 0) s_base = atomicAdd(&cbase[li * CNT_STRIDE], s_cnt);
  if (tid < NBUCKET && s_bh[tid] > 0)
    atomicAdd(&cbase[(16 + li * NBUCKET + tid) * CNT_STRIDE], s_bh[tid]);
  __syncthreads();
  for (int j = 0; j < nsv; ++j) {
    unsigned int pos = s_base + local + (unsigned int)j;
    if (pos < CAP) {
      unsigned long long key = ((unsigned long long)__float_as_uint(svals[j]) << 32)
                             | (unsigned long long)(~sidx[j]);
      lists[(size_t)li * CAP + pos] = key;
    }
  }

  // Phase 5 (src0 only): block-reduce dense loss terms -> fixed-point atomics
  if (src == 0) {
    shA[tid] = tsum; shI[tid] = vcnt;
    __syncthreads();
    for (int s = 128; s > 0; s >>= 1) {
      if (tid < s) { shA[tid] += shA[tid + s]; shI[tid] += shI[tid + s]; }
      __syncthreads();
    }
    if (tid == 0) {
      long long fp = (long long)((double)shA[0] * 4294967296.0);
      atomicAdd(&accum[0], (unsigned long long)fp);
      atomicAdd(&accum[1], (unsigned long long)shI[0]);
    }
  }
}

// Exact top-512 per (source,image) via bucket counts -> single gather scan ->
// bitonic sort by full 64-bit key.
// src0 -> kp1 out. src1 -> scatter 5x5 gaussian taps into gtbuf + affected list.
#define NT 1024
__global__ __launch_bounds__(NT) void k_topk3(const unsigned long long* __restrict__ lists,
                                              const unsigned int* __restrict__ cbase,
                                              float* __restrict__ out, float* __restrict__ gtbuf,
                                              unsigned int* __restrict__ alcnt,
                                              unsigned int* __restrict__ alist) {
  int li = blockIdx.x;             // 0..15
  int src = li >> 3, b = li & 7;
  int tid = threadIdx.x;

  __shared__ unsigned long long sbuf[GCAP];
  __shared__ unsigned int s_bc[NBUCKET];
  __shared__ int s_bb;
  __shared__ unsigned int s_nsel;
  __shared__ unsigned int s_abase;

  unsigned int N = cbase[li * CNT_STRIDE]; if (N > CAP) N = CAP;
  if (tid < NBUCKET) s_bc[tid] = cbase[(16 + li * NBUCKET + tid) * CNT_STRIDE];
  if (tid == 0) s_nsel = 0;
  __syncthreads();

  if (tid == 0) {
    unsigned int want = (N < TOPK) ? N : TOPK;
    int bb = NBUCKET;              // gather nothing if want == 0
    if (want > 0) {
      unsigned int cum = 0;
      for (int bk = NBUCKET - 1; bk >= 1; --bk) {
        cum += s_bc[bk];
        bb = bk;
        if (cum >= want) break;
      }
    }
    s_bb = bb;
  }
  __syncthreads();
  int bb = s_bb;

  // single gather scan with wave-aggregated LDS push
  const unsigned long long* list = lists + (size_t)li * CAP;
  int lane = tid & 63;
  for (unsigned int i = tid; i < N; i += NT) {
    unsigned long long k = list[i];
    float v = __uint_as_float((unsigned int)(k >> 32));
    bool pred = (vbucket(v) >= bb);
    unsigned long long mask = __ballot(pred);
    if (mask) {
      int leader = __ffsll((long long)mask) - 1;
      unsigned int cnt = (unsigned int)__popcll(mask);
      unsigned int bp = 0;
      if (lane == leader) bp = atomicAdd(&s_nsel, cnt);
      bp = __shfl(bp, leader, 64);
      if (pred) {
        unsigned int pos = bp + (unsigned int)__popcll(mask & ((1ULL << lane) - 1ULL));
        if (pos < GCAP) sbuf[pos] = k;
      }
    }
  }
  __syncthreads();
  unsigned int total = s_nsel; if (total > GCAP) total = GCAP;

  // pad to S = max(512, next_pow2(total)) <= GCAP, sort descending by full key
  unsigned int S = 512; while (S < total) S <<= 1;
  for (unsigned int i = tid; i < S; i += NT)
    if (i >= total) sbuf[i] = 0ULL;
  __syncthreads();

  for (unsigned int k2 = 2; k2 <= S; k2 <<= 1) {
    for (unsigned int j = k2 >> 1; j > 0; j >>= 1) {
      for (unsigned int i = tid; i < S; i += NT) {
        unsigned int ixj = i ^ j;
        if (ixj > i) {
          bool desc = ((i & k2) == 0);
          unsigned long long a = sbuf[i], c = sbuf[ixj];
          bool sw = desc ? (a < c) : (a > c);
          if (sw) { sbuf[i] = c; sbuf[ixj] = a; }
        }
      }
      __syncthreads();
    }
  }

  if (src == 0) {
    for (int r = tid; r < TOPK; r += NT) {
      unsigned long long k = sbuf[r];
      unsigned int idx = (k == 0ULL) ? 0u : ~(unsigned int)(k & 0xFFFFFFFFULL);
      int yy = (int)(idx / NW), xx = (int)(idx % NW);
      out[1 + ((b * TOPK) + r) * 2 + 0] = (float)yy;
      out[1 + ((b * TOPK) + r) * 2 + 1] = (float)xx;
    }
  } else {
    // winners = leading nonzero entries (sorted desc, zeros trail)
    unsigned int nw = (total < TOPK) ? total : TOPK;
    if (tid == 0) s_abase = (nw > 0) ? atomicAdd(alcnt, nw * 25u) : 0u;
    __syncthreads();
    unsigned int abase = s_abase;
    const float gw[5] = {G2, G1, G0, G1, G2};
    for (unsigned int r = tid; r < nw; r += NT) {
      unsigned long long k = sbuf[r];
      unsigned int idx = ~(unsigned int)(k & 0xFFFFFFFFULL);
      float val = __uint_as_float((unsigned int)(k >> 32));
      int y = (int)(idx / NW), x = (int)(idx % NW);
      // winners are >=8 px from edges; radius-2 support always in-bounds
      #pragma unroll
      for (int dy = -2; dy <= 2; ++dy) {
        #pragma unroll
        for (int dx = -2; dx <= 2; ++dx) {
          float w = val * gw[dy + 2] * gw[dx + 2];
          unsigned int t = (unsigned int)(b * NHW + (y + dy) * NW + (x + dx));
          atomicAdd(&gtbuf[t], w);
          unsigned int pos = abase + r * 25u + (unsigned int)((dy + 2) * 5 + (dx + 2));
          alist[pos] = t;
        }
      }
    }
  }
}

// Sparse correction: Sum over affected pixels of (gt^2 - 2*s1*gt)*v.
// atomicExch dedups duplicate list entries AND restores gtbuf to zero.
__global__ void k_correct(const float* __restrict__ score1, const float* __restrict__ homo,
                          float* __restrict__ gtbuf, const unsigned int* __restrict__ alcnt,
                          const unsigned int* __restrict__ alist,
                          unsigned long long* __restrict__ accum) {
  unsigned int n = *alcnt; if (n > ALCAP) n = ALCAP;
  unsigned int i = blockIdx.x * 256 + threadIdx.x;
  float term = 0.f;
  if (i < n) {
    unsigned int t = alist[i];
    float gt = atomicExch(&gtbuf[t], 0.f);
    if (gt != 0.f) {
      int b = (int)(t / NHW);
      int p = (int)(t % NHW);
      int y = p / NW, x = p % NW;
      float s1 = bordered(score1, b, y, x);
      const float* hm = homo + b * 9;
      float v = visv(hm[0], hm[1], hm[2], hm[3], hm[4], hm[5], hm[6], hm[7], hm[8], x, y);
      term = (gt - 2.f * s1) * gt * v;
    }
  }
  __shared__ float shA[256];
  int tid = threadIdx.x;
  shA[tid] = term;
  __syncthreads();
  for (int s = 128; s > 0; s >>= 1) {
    if (tid < s) shA[tid] += shA[tid + s];
    __syncthreads();
  }
  if (tid == 0) {
    long long fp = (long long)((double)shA[0] * 4294967296.0);
    atomicAdd(&accum[0], (unsigned long long)fp);
  }
}

__global__ void k_final3(const unsigned long long* __restrict__ accum, float* __restrict__ out) {
  if (threadIdx.x == 0) {
    double ts = (double)(long long)accum[0] / 4294967296.0;
    double n = (double)accum[1];
    out[0] = (float)(100.0 * ts / n);
  }
}

extern "C" void kernel_launch(void* const* d_in, const int* in_sizes, int n_in,
                              void* d_out, int out_size, void* d_ws, size_t ws_size,
                              hipStream_t stream) {
  const float* score1 = (const float*)d_in[0];
  const float* score2 = (const float*)d_in[1];
  const float* homo   = (const float*)d_in[2];
  float* out = (float*)d_out;

  // workspace layout
  float* gtbuf = (float*)d_ws;                                    // NBHW f32 (memset)
  unsigned long long* lists = (unsigned long long*)(gtbuf + NBHW); // 16*CAP u64
  const int NCNT = (16 + 16 * NBUCKET) * CNT_STRIDE;              // survivor counters
  unsigned int* cbase = (unsigned int*)(lists + (size_t)16 * CAP);
  unsigned int* alcnt = cbase + NCNT;                             // 1 u32 (own cacheline block)
  unsigned long long* accum = (unsigned long long*)(alcnt + CNT_STRIDE); // 4 u64
  unsigned int* alist = (unsigned int*)(accum + 4);               // ALCAP u32 (no memset)

  size_t required = (size_t)NBHW * 4 + (size_t)16 * CAP * 8
                  + (size_t)(NCNT + CNT_STRIDE) * 4 + 32 + (size_t)ALCAP * 4;
  if (ws_size < required) return;

  hipMemsetAsync(gtbuf, 0, (size_t)NBHW * sizeof(float), stream);
  hipMemsetAsync(cbase, 0, (size_t)(NCNT + CNT_STRIDE) * 4 + 32, stream);

  dim3 gnms(NW / TW, NH / TH, 16);    // 10 x 32 x 16
  k_nms3<<<gnms, 256, 0, stream>>>(score1, score2, homo, lists, cbase, accum);
  k_topk3<<<16, NT, 0, stream>>>(lists, cbase, out, gtbuf, alcnt, alist);
  k_correct<<<(ALCAP + 255) / 256, 256, 0, stream>>>(score1, homo, gtbuf, alcnt, alist, accum);
  k_final3<<<1, 64, 0, stream>>>(accum, out);
}

// Round 8
// 162.294 us; speedup vs baseline: 1.0150x; 1.0150x over previous
//
#include <hip/hip_runtime.h>

#define NB 8
#define NH 512
#define NW 640
#define NHW (NH*NW)
#define NBHW (NB*NHW)
#define TOPK 512
#define CAP 40960
#define PAD 8
#define CNT_STRIDE 64   // one counter per 256B cacheline
#define NBUCKET 32
#define GCAP 4096       // topk gather capacity (32 KB LDS)
#define ALCAP (16 * TOPK * 25)   // affected-pixel list capacity: 8 img * 512 * 25 (exact bound)

// NMS tile geometry (block = 256 threads)
#define TW 64
#define TH 16

// Gaussian taps exp(-2 d^2); |d|>=3 taps are <=1.52e-8 -> negligible, radius 2 used
#define G0 1.0f
#define G1 0.1353352832366127f
#define G2 3.3546262790251185e-4f

__device__ __forceinline__ float bordered(const float* __restrict__ img, int b, int y, int x) {
  if (y < PAD || y >= NH - PAD || x < PAD || x >= NW - PAD) return 0.f;
  return img[b * NHW + y * NW + x];
}

// Monotone (weakly increasing in val) bucket index, fine-grained near 1.0.
__device__ __forceinline__ int vbucket(float val) {
  int d = 0x3F800000 - (int)__float_as_uint(val);
  if (d <= 0) return NBUCKET - 1;        // val >= 1.0
  int c = __clz(d);                       // 2..31
  return c > 30 ? 30 : c;
}

__device__ __forceinline__ void corner(const float* __restrict__ img, float cx, float cy,
                                       float wgt, float& acc) {
  float valid = (cx >= 0.f && cx <= (float)(NW - 1) && cy >= 0.f && cy <= (float)(NH - 1)) ? 1.f : 0.f;
  float xc = fminf(fmaxf(cx, 0.f), (float)(NW - 1));
  float yc = fminf(fmaxf(cy, 0.f), (float)(NH - 1));
  int xi = (int)xc, yi = (int)yc;
  acc += wgt * img[yi * NW + xi] * valid;
}

// Division-free visibility: v=1 iff x2 in (-1,NW) and y2 in (-1,NH), x2=X/Z.
// Sign-safe via multiplying both sides by Z (Z=0/NaN -> all tests false -> 0,
// matching the reference's inf/NaN comparison behavior).
__device__ __forceinline__ float vis_quad(float h0, float h1, float h2, float h3, float h4,
                                          float h5, float h6, float h7, float h8,
                                          float xf, float yf) {
  float X = h0 * xf + h1 * yf + h2;
  float Y = h3 * xf + h4 * yf + h5;
  float Z = h6 * xf + h7 * yf + h8;
  bool ok = ((X + Z) * Z > 0.f) & ((640.f * Z - X) * Z > 0.f)
          & ((Y + Z) * Z > 0.f) & ((512.f * Z - Y) * Z > 0.f);
  return ok ? 1.f : 0.f;
}

// Fused warp + border-filter + 5x5 separable NMS + bucket counts.
// src==0 blocks additionally accumulate the dense loss terms Sum(s1^2 * v), Sum(v)
// (s1 already in LDS; v analytic, division-free).
__global__ void k_nms3(const float* __restrict__ score1, const float* __restrict__ score2,
                       const float* __restrict__ homo,
                       unsigned long long* __restrict__ lists, unsigned int* __restrict__ cbase,
                       unsigned long long* __restrict__ accum) {
  int bx = blockIdx.x, by = blockIdx.y;
  int src = blockIdx.z >> 3, b = blockIdx.z & 7;
  int tid = threadIdx.x;

  __shared__ float in[TH + 4][TW + 4];     // 20 x 68
  __shared__ float hmax[TH + 4][TW];       // 20 x 64
  __shared__ unsigned int s_cnt;
  __shared__ unsigned int s_base;
  __shared__ unsigned int s_bh[NBUCKET];
  __shared__ float shA[256];
  __shared__ unsigned int shI[256];

  if (tid == 0) s_cnt = 0;
  if (tid < NBUCKET) s_bh[tid] = 0;

  const float* hm = homo + b * 9;
  float h0 = hm[0], h1 = hm[1], h2 = hm[2];
  float h3 = hm[3], h4 = hm[4], h5 = hm[5];
  float h6 = hm[6], h7 = hm[7], h8 = hm[8];

  // Phase 1: stage tile (+2 halo) into LDS, border-filtered.
  for (int i = tid; i < (TH + 4) * (TW + 4); i += 256) {
    int r = i / (TW + 4), c = i % (TW + 4);
    int gy = by * TH + r - 2, gx = bx * TW + c - 2;
    float v = 0.f;
    if (src == 0) {
      v = bordered(score1, b, gy, gx);
    } else {
      bool inb = (gy >= PAD && gy < NH - PAD && gx >= PAD && gx < NW - PAD);
      if (inb) {
        float xf = (float)gx, yf = (float)gy;
        float X = h0 * xf + h1 * yf + h2;
        float Y = h3 * xf + h4 * yf + h5;
        float Z = h6 * xf + h7 * yf + h8;
        float rz = __builtin_amdgcn_rcpf(Z);     // 1-ulp; classification-only impact
        float x2 = X * rz, y2 = Y * rz;
        float x0 = floorf(x2), y0 = floorf(y2);
        float x1 = x0 + 1.f, y1 = y0 + 1.f;
        float wa = (x1 - x2) * (y1 - y2);
        float wb = (x2 - x0) * (y1 - y2);
        float wc = (x1 - x2) * (y2 - y0);
        float wd = (x2 - x0) * (y2 - y0);
        const float* img = score2 + b * NHW;
        float acc = 0.f;
        corner(img, x0, y0, wa, acc);
        corner(img, x1, y0, wb, acc);
        corner(img, x0, y1, wc, acc);
        corner(img, x1, y1, wd, acc);
        v = acc;
      }
    }
    in[r][c] = v;
  }
  __syncthreads();

  // Phase 2: horizontal 5-max
  for (int i = tid; i < (TH + 4) * TW; i += 256) {
    int r = i / TW, c = i % TW;
    float m = fmaxf(fmaxf(fmaxf(in[r][c], in[r][c + 1]), fmaxf(in[r][c + 2], in[r][c + 3])),
                    in[r][c + 4]);
    hmax[r][c] = m;
  }
  __syncthreads();

  // Phase 3: vertical 5-max + survivor detection; src0 also dense loss terms
  int nsv = 0;
  float svals[4];
  unsigned int sidx[4];
  float tsum = 0.f;
  unsigned int vcnt = 0;
  #pragma unroll
  for (int it = 0; it < (TH * TW) / 256; ++it) {
    int i = it * 256 + tid;
    int r = i / TW, c = i % TW;
    int gy = by * TH + r, gx = bx * TW + c;
    float val = in[r + 2][c + 2];
    if (src == 0) {
      float v = vis_quad(h0, h1, h2, h3, h4, h5, h6, h7, h8, (float)gx, (float)gy);
      tsum += val * val * v;
      vcnt += (v > 0.f) ? 1u : 0u;
    }
    if (val > 0.f) {   // NMS_THRESH = 0
      float m = fmaxf(fmaxf(fmaxf(hmax[r][c], hmax[r + 1][c]), fmaxf(hmax[r + 2][c], hmax[r + 3][c])),
                      hmax[r + 4][c]);
      if (m == val) {
        svals[nsv] = val;
        sidx[nsv] = (unsigned int)(gy * NW + gx);
        ++nsv;
      }
    }
  }

  // Phase 4: block-aggregated push + bucket counts
  unsigned int local = 0;
  if (nsv > 0) local = atomicAdd(&s_cnt, (unsigned int)nsv);
  for (int j = 0; j < nsv; ++j) atomicAdd(&s_bh[vbucket(svals[j])], 1u);
  __syncthreads();
  int li = src * NB + b;
  if (tid == 0 && s_cnt > 0) s_base = atomicAdd(&cbase[li * CNT_STRIDE], s_cnt);
  if (tid < NBUCKET && s_bh[tid] > 0)
    atomicAdd(&cbase[(16 + li * NBUCKET + tid) * CNT_STRIDE], s_bh[tid]);
  __syncthreads();
  for (int j = 0; j < nsv; ++j) {
    unsigned int pos = s_base + local + (unsigned int)j;
    if (pos < CAP) {
      unsigned long long key = ((unsigned long long)__float_as_uint(svals[j]) << 32)
                             | (unsigned long long)(~sidx[j]);
      lists[(size_t)li * CAP + pos] = key;
    }
  }

  // Phase 5 (src0 only): block-reduce dense loss terms -> fixed-point atomics
  if (src == 0) {
    shA[tid] = tsum; shI[tid] = vcnt;
    __syncthreads();
    for (int s = 128; s > 0; s >>= 1) {
      if (tid < s) { shA[tid] += shA[tid + s]; shI[tid] += shI[tid + s]; }
      __syncthreads();
    }
    if (tid == 0) {
      long long fp = (long long)((double)shA[0] * 4294967296.0);
      atomicAdd(&accum[0], (unsigned long long)fp);
      atomicAdd(&accum[1], (unsigned long long)shI[0]);
    }
  }
}

// Exact top-512 per (source,image) via bucket counts -> single gather scan ->
// bitonic sort by full 64-bit key.
// src0 -> kp1 out. src1 -> scatter 5x5 gaussian taps into gtbuf + affected list.
#define NT 1024
__global__ __launch_bounds__(NT) void k_topk3(const unsigned long long* __restrict__ lists,
                                              const unsigned int* __restrict__ cbase,
                                              float* __restrict__ out, float* __restrict__ gtbuf,
                                              unsigned int* __restrict__ alcnt,
                                              unsigned int* __restrict__ alist) {
  int li = blockIdx.x;             // 0..15
  int src = li >> 3, b = li & 7;
  int tid = threadIdx.x;

  __shared__ unsigned long long sbuf[GCAP];
  __shared__ unsigned int s_bc[NBUCKET];
  __shared__ int s_bb;
  __shared__ unsigned int s_nsel;
  __shared__ unsigned int s_abase;

  unsigned int N = cbase[li * CNT_STRIDE]; if (N > CAP) N = CAP;
  if (tid < NBUCKET) s_bc[tid] = cbase[(16 + li * NBUCKET + tid) * CNT_STRIDE];
  if (tid == 0) s_nsel = 0;
  __syncthreads();

  if (tid == 0) {
    unsigned int want = (N < TOPK) ? N : TOPK;
    int bb = NBUCKET;              // gather nothing if want == 0
    if (want > 0) {
      unsigned int cum = 0;
      for (int bk = NBUCKET - 1; bk >= 1; --bk) {
        cum += s_bc[bk];
        bb = bk;
        if (cum >= want) break;
      }
    }
    s_bb = bb;
  }
  __syncthreads();
  int bb = s_bb;

  // single gather scan with wave-aggregated LDS push
  const unsigned long long* list = lists + (size_t)li * CAP;
  int lane = tid & 63;
  for (unsigned int i = tid; i < N; i += NT) {
    unsigned long long k = list[i];
    float v = __uint_as_float((unsigned int)(k >> 32));
    bool pred = (vbucket(v) >= bb);
    unsigned long long mask = __ballot(pred);
    if (mask) {
      int leader = __ffsll((long long)mask) - 1;
      unsigned int cnt = (unsigned int)__popcll(mask);
      unsigned int bp = 0;
      if (lane == leader) bp = atomicAdd(&s_nsel, cnt);
      bp = __shfl(bp, leader, 64);
      if (pred) {
        unsigned int pos = bp + (unsigned int)__popcll(mask & ((1ULL << lane) - 1ULL));
        if (pos < GCAP) sbuf[pos] = k;
      }
    }
  }
  __syncthreads();
  unsigned int total = s_nsel; if (total > GCAP) total = GCAP;

  // pad to S = max(512, next_pow2(total)) <= GCAP, sort descending by full key
  unsigned int S = 512; while (S < total) S <<= 1;
  for (unsigned int i = tid; i < S; i += NT)
    if (i >= total) sbuf[i] = 0ULL;
  __syncthreads();

  for (unsigned int k2 = 2; k2 <= S; k2 <<= 1) {
    for (unsigned int j = k2 >> 1; j > 0; j >>= 1) {
      for (unsigned int i = tid; i < S; i += NT) {
        unsigned int ixj = i ^ j;
        if (ixj > i) {
          bool desc = ((i & k2) == 0);
          unsigned long long a = sbuf[i], c = sbuf[ixj];
          bool sw = desc ? (a < c) : (a > c);
          if (sw) { sbuf[i] = c; sbuf[ixj] = a; }
        }
      }
      __syncthreads();
    }
  }

  if (src == 0) {
    for (int r = tid; r < TOPK; r += NT) {
      unsigned long long k = sbuf[r];
      unsigned int idx = (k == 0ULL) ? 0u : ~(unsigned int)(k & 0xFFFFFFFFULL);
      int yy = (int)(idx / NW), xx = (int)(idx % NW);
      out[1 + ((b * TOPK) + r) * 2 + 0] = (float)yy;
      out[1 + ((b * TOPK) + r) * 2 + 1] = (float)xx;
    }
  } else {
    // winners = leading nonzero entries (sorted desc, zeros trail)
    unsigned int nw = (total < TOPK) ? total : TOPK;
    if (tid == 0) s_abase = (nw > 0) ? atomicAdd(alcnt, nw * 25u) : 0u;
    __syncthreads();
    unsigned int abase = s_abase;
    const float gw[5] = {G2, G1, G0, G1, G2};
    for (unsigned int r = tid; r < nw; r += NT) {
      unsigned long long k = sbuf[r];
      unsigned int idx = ~(unsigned int)(k & 0xFFFFFFFFULL);
      float val = __uint_as_float((unsigned int)(k >> 32));
      int y = (int)(idx / NW), x = (int)(idx % NW);
      // winners are >=8 px from edges; radius-2 support always in-bounds
      #pragma unroll
      for (int dy = -2; dy <= 2; ++dy) {
        #pragma unroll
        for (int dx = -2; dx <= 2; ++dx) {
          float w = val * gw[dy + 2] * gw[dx + 2];
          unsigned int t = (unsigned int)(b * NHW + (y + dy) * NW + (x + dx));
          atomicAdd(&gtbuf[t], w);
          unsigned int pos = abase + r * 25u + (unsigned int)((dy + 2) * 5 + (dx + 2));
          alist[pos] = t;
        }
      }
    }
  }
}

// Sparse correction: Sum over affected pixels of (gt^2 - 2*s1*gt)*v.
// atomicExch dedups duplicate list entries AND restores gtbuf to zero.
__global__ void k_correct(const float* __restrict__ score1, const float* __restrict__ homo,
                          float* __restrict__ gtbuf, const unsigned int* __restrict__ alcnt,
                          const unsigned int* __restrict__ alist,
                          unsigned long long* __restrict__ accum) {
  unsigned int n = *alcnt; if (n > ALCAP) n = ALCAP;
  unsigned int i = blockIdx.x * 256 + threadIdx.x;
  float term = 0.f;
  if (i < n) {
    unsigned int t = alist[i];
    float gt = atomicExch(&gtbuf[t], 0.f);
    if (gt != 0.f) {
      int b = (int)(t / NHW);
      int p = (int)(t % NHW);
      int y = p / NW, x = p % NW;
      float s1 = bordered(score1, b, y, x);
      const float* hm = homo + b * 9;
      float v = vis_quad(hm[0], hm[1], hm[2], hm[3], hm[4], hm[5], hm[6], hm[7], hm[8],
                         (float)x, (float)y);
      term = (gt - 2.f * s1) * gt * v;
    }
  }
  __shared__ float shA[256];
  int tid = threadIdx.x;
  shA[tid] = term;
  __syncthreads();
  for (int s = 128; s > 0; s >>= 1) {
    if (tid < s) shA[tid] += shA[tid + s];
    __syncthreads();
  }
  if (tid == 0) {
    long long fp = (long long)((double)shA[0] * 4294967296.0);
    atomicAdd(&accum[0], (unsigned long long)fp);
  }
}

__global__ void k_final3(const unsigned long long* __restrict__ accum, float* __restrict__ out) {
  if (threadIdx.x == 0) {
    double ts = (double)(long long)accum[0] / 4294967296.0;
    double n = (double)accum[1];
    out[0] = (float)(100.0 * ts / n);
  }
}

extern "C" void kernel_launch(void* const* d_in, const int* in_sizes, int n_in,
                              void* d_out, int out_size, void* d_ws, size_t ws_size,
                              hipStream_t stream) {
  const float* score1 = (const float*)d_in[0];
  const float* score2 = (const float*)d_in[1];
  const float* homo   = (const float*)d_in[2];
  float* out = (float*)d_out;

  // workspace layout
  float* gtbuf = (float*)d_ws;                                    // NBHW f32 (memset)
  unsigned long long* lists = (unsigned long long*)(gtbuf + NBHW); // 16*CAP u64
  const int NCNT = (16 + 16 * NBUCKET) * CNT_STRIDE;              // survivor counters
  unsigned int* cbase = (unsigned int*)(lists + (size_t)16 * CAP);
  unsigned int* alcnt = cbase + NCNT;                             // 1 u32 (own cacheline block)
  unsigned long long* accum = (unsigned long long*)(alcnt + CNT_STRIDE); // 4 u64
  unsigned int* alist = (unsigned int*)(accum + 4);               // ALCAP u32 (no memset)

  size_t required = (size_t)NBHW * 4 + (size_t)16 * CAP * 8
                  + (size_t)(NCNT + CNT_STRIDE) * 4 + 32 + (size_t)ALCAP * 4;
  if (ws_size < required) return;

  hipMemsetAsync(gtbuf, 0, (size_t)NBHW * sizeof(float), stream);
  hipMemsetAsync(cbase, 0, (size_t)(NCNT + CNT_STRIDE) * 4 + 32, stream);

  dim3 gnms(NW / TW, NH / TH, 16);    // 10 x 32 x 16
  k_nms3<<<gnms, 256, 0, stream>>>(score1, score2, homo, lists, cbase, accum);
  k_topk3<<<16, NT, 0, stream>>>(lists, cbase, out, gtbuf, alcnt, alist);
  k_correct<<<(ALCAP + 255) / 256, 256, 0, stream>>>(score1, homo, gtbuf, alcnt, alist, accum);
  k_final3<<<1, 64, 0, stream>>>(accum, out);
}

// Round 9
// 146.403 us; speedup vs baseline: 1.1251x; 1.1085x over previous
//
#include <hip/hip_runtime.h>

#define NB 8
#define NH 512
#define NW 640
#define NHW (NH*NW)
#define NBHW (NB*NHW)
#define TOPK 512
#define CAP 40960
#define PAD 8
#define CNT_STRIDE 64   // one counter per 256B cacheline
#define NBUCKET 32
#define GCAP 4096       // topk gather capacity (32 KB LDS)

// NMS tile geometry (block = 256 threads)
#define TW 64
#define TH 32
#define INH 36          // staged rows:  gy in [by*32-2, by*32+34)
#define INW 72          // staged cols:  gx in [bx*64-4, bx*64+68); cols 2..69 used

// Gaussian taps exp(-2 d^2); |d|>=3 taps are <=1.52e-8 -> negligible, radius 2 used
#define G0 1.0f
#define G1 0.1353352832366127f
#define G2 3.3546262790251185e-4f

__device__ __forceinline__ float bordered(const float* __restrict__ img, int b, int y, int x) {
  if (y < PAD || y >= NH - PAD || x < PAD || x >= NW - PAD) return 0.f;
  return img[b * NHW + y * NW + x];
}

// Monotone (weakly increasing in val) bucket index, fine-grained near 1.0.
__device__ __forceinline__ int vbucket(float val) {
  int d = 0x3F800000 - (int)__float_as_uint(val);
  if (d <= 0) return NBUCKET - 1;
  int c = __clz(d);
  return c > 30 ? 30 : c;
}

__device__ __forceinline__ void corner(const float* __restrict__ img, float cx, float cy,
                                       float wgt, float& acc) {
  float valid = (cx >= 0.f && cx <= (float)(NW - 1) && cy >= 0.f && cy <= (float)(NH - 1)) ? 1.f : 0.f;
  float xc = fminf(fmaxf(cx, 0.f), (float)(NW - 1));
  float yc = fminf(fmaxf(cy, 0.f), (float)(NH - 1));
  int xi = (int)xc, yi = (int)yc;
  acc += wgt * img[yi * NW + xi] * valid;
}

// Division-free visibility: v=1 iff x2 in (-1,NW) and y2 in (-1,NH), x2=X/Z.
__device__ __forceinline__ float vis_quad(float h0, float h1, float h2, float h3, float h4,
                                          float h5, float h6, float h7, float h8,
                                          float xf, float yf) {
  float X = h0 * xf + h1 * yf + h2;
  float Y = h3 * xf + h4 * yf + h5;
  float Z = h6 * xf + h7 * yf + h8;
  bool ok = ((X + Z) * Z > 0.f) & ((640.f * Z - X) * Z > 0.f)
          & ((Y + Z) * Z > 0.f) & ((512.f * Z - Y) * Z > 0.f);
  return ok ? 1.f : 0.f;
}

// Fused warp + border-filter + 5x5 separable NMS + bucket counts (+dense loss, src0)
// (+gtbuf tile zeroing, src1). 4 barriers per block.
__global__ __launch_bounds__(256) void k_nms4(
    const float* __restrict__ score1, const float* __restrict__ score2,
    const float* __restrict__ homo, float* __restrict__ gtbuf,
    unsigned long long* __restrict__ lists, unsigned int* __restrict__ cbase,
    unsigned long long* __restrict__ accum) {
  int bx = blockIdx.x, by = blockIdx.y;
  int src = blockIdx.z >> 3, b = blockIdx.z & 7;
  int tid = threadIdx.x;

  __shared__ float in[INH][INW];       // 10.1 KB
  __shared__ float hmax[INH][TW];      // 9.0 KB
  __shared__ unsigned int s_cnt, s_base;
  __shared__ unsigned int s_bh[NBUCKET];
  __shared__ float s_wsum[4];
  __shared__ unsigned int s_wcnt[4];

  if (tid == 0) { s_cnt = 0; s_base = 0; }
  if (tid < NBUCKET) s_bh[tid] = 0;

  const float* hm = homo + b * 9;
  float h0 = hm[0], h1 = hm[1], h2 = hm[2];
  float h3 = hm[3], h4 = hm[4], h5 = hm[5];
  float h6 = hm[6], h7 = hm[7], h8 = hm[8];

  int y0t = by * TH, x0t = bx * TW;

  // Phase 1: stage tile into LDS (border-filtered values)
  if (src == 0) {
    // float4 staging from score1: 36 rows x 18 float4 (covers cols -4..67)
    for (int i = tid; i < INH * 18; i += 256) {
      int r = i / 18, c4 = i % 18;
      int gy = y0t + r - 2;
      int gx0 = x0t - 4 + c4 * 4;
      float4 v = make_float4(0.f, 0.f, 0.f, 0.f);
      if (gy >= PAD && gy < NH - PAD) {
        const float4* p = (const float4*)(score1 + (size_t)b * NHW + (size_t)gy * NW + gx0);
        float4 raw = *p;
        v.x = (gx0 + 0 >= PAD && gx0 + 0 < NW - PAD) ? raw.x : 0.f;
        v.y = (gx0 + 1 >= PAD && gx0 + 1 < NW - PAD) ? raw.y : 0.f;
        v.z = (gx0 + 2 >= PAD && gx0 + 2 < NW - PAD) ? raw.z : 0.f;
        v.w = (gx0 + 3 >= PAD && gx0 + 3 < NW - PAD) ? raw.w : 0.f;
      }
      *(float4*)&in[r][c4 * 4] = v;
    }
  } else {
    // zero this tile's gtbuf region (32 rows x 16 float4, coalesced)
    for (int i = tid; i < TH * 16; i += 256) {
      int r = i >> 4, c = i & 15;
      ((float4*)(gtbuf + (size_t)b * NHW + (size_t)(y0t + r) * NW + x0t))[c] =
          make_float4(0.f, 0.f, 0.f, 0.f);
    }
    // warp staging: 36 rows x 68 cols (LDS cols 2..69)
    for (int i = tid; i < INH * 68; i += 256) {
      int r = i / 68, c = i % 68;
      int gy = y0t + r - 2, gx = x0t - 2 + c;
      float v = 0.f;
      if (gy >= PAD && gy < NH - PAD && gx >= PAD && gx < NW - PAD) {
        float xf = (float)gx, yf = (float)gy;
        float X = h0 * xf + h1 * yf + h2;
        float Y = h3 * xf + h4 * yf + h5;
        float Z = h6 * xf + h7 * yf + h8;
        float rz = __builtin_amdgcn_rcpf(Z);
        float x2 = X * rz, y2 = Y * rz;
        float x0 = floorf(x2), y0 = floorf(y2);
        float x1 = x0 + 1.f, y1 = y0 + 1.f;
        float wa = (x1 - x2) * (y1 - y2);
        float wb = (x2 - x0) * (y1 - y2);
        float wc = (x1 - x2) * (y2 - y0);
        float wd = (x2 - x0) * (y2 - y0);
        const float* img = score2 + b * NHW;
        float acc = 0.f;
        corner(img, x0, y0, wa, acc);
        corner(img, x1, y0, wb, acc);
        corner(img, x0, y1, wc, acc);
        corner(img, x1, y1, wd, acc);
        v = acc;
      }
      in[r][c + 2] = v;
    }
  }
  __syncthreads();

  // Phase 2: horizontal 5-max. hmax[r][c] = max(in[r][c+2 .. c+6])
  for (int i = tid; i < INH * TW; i += 256) {
    int r = i >> 6, c = i & 63;
    float m = fmaxf(fmaxf(fmaxf(in[r][c + 2], in[r][c + 3]), fmaxf(in[r][c + 4], in[r][c + 5])),
                    in[r][c + 6]);
    hmax[r][c] = m;
  }
  __syncthreads();

  // Phase 3: vertical 5-max + survivor detection; src0 also dense loss terms
  int nsv = 0;
  float sv[8];
  unsigned int si[8];
  float tsum = 0.f;
  int vcnt = 0;
  #pragma unroll
  for (int it = 0; it < (TH * TW) / 256; ++it) {
    int i = it * 256 + tid;
    int r = i >> 6, c = i & 63;
    int gy = y0t + r, gx = x0t + c;
    float val = in[r + 2][c + 4];
    if (src == 0) {
      float v = vis_quad(h0, h1, h2, h3, h4, h5, h6, h7, h8, (float)gx, (float)gy);
      tsum += val * val * v;
      vcnt += (v > 0.f) ? 1 : 0;
    }
    if (val > 0.f) {   // NMS_THRESH = 0
      float m = fmaxf(fmaxf(fmaxf(hmax[r][c], hmax[r + 1][c]), fmaxf(hmax[r + 2][c], hmax[r + 3][c])),
                      hmax[r + 4][c]);
      if (m == val) {
        sv[nsv] = val;
        si[nsv] = (unsigned int)(gy * NW + gx);
        ++nsv;
      }
    }
  }

  // Phase 4: LDS bookkeeping + wave reduce, then 2 barriers total
  unsigned int local = 0;
  if (nsv > 0) local = atomicAdd(&s_cnt, (unsigned int)nsv);
  #pragma unroll
  for (int j = 0; j < 8; ++j)
    if (j < nsv) atomicAdd(&s_bh[vbucket(sv[j])], 1u);

  if (src == 0) {
    for (int m = 1; m < 64; m <<= 1) {
      tsum += __shfl_xor(tsum, m, 64);
      vcnt += __shfl_xor(vcnt, m, 64);
    }
    if ((tid & 63) == 0) { s_wsum[tid >> 6] = tsum; s_wcnt[tid >> 6] = (unsigned int)vcnt; }
  }
  __syncthreads();

  int li = src * NB + b;
  if (tid == 0) {
    if (s_cnt > 0) s_base = atomicAdd(&cbase[li * CNT_STRIDE], s_cnt);
    if (src == 0) {
      float ts = s_wsum[0] + s_wsum[1] + s_wsum[2] + s_wsum[3];
      unsigned int vc = s_wcnt[0] + s_wcnt[1] + s_wcnt[2] + s_wcnt[3];
      long long fp = (long long)((double)ts * 4294967296.0);
      atomicAdd(&accum[0], (unsigned long long)fp);
      atomicAdd(&accum[1], (unsigned long long)vc);
    }
  }
  if (tid < NBUCKET && s_bh[tid] > 0)
    atomicAdd(&cbase[(16 + li * NBUCKET + tid) * CNT_STRIDE], s_bh[tid]);
  __syncthreads();

  unsigned int base = s_base;
  #pragma unroll
  for (int j = 0; j < 8; ++j) {
    if (j < nsv) {
      unsigned int pos = base + local + (unsigned int)j;
      if (pos < CAP) {
        unsigned long long key = ((unsigned long long)__float_as_uint(sv[j]) << 32)
                               | (unsigned long long)(~si[j]);
        lists[(size_t)li * CAP + pos] = key;
      }
    }
  }
}

// Exact top-512 per (source,image): bucket counts -> one gather scan -> bitonic sort.
// src0 -> kp1. src1 -> in-block gaussian scatter + dedup correction (owns image b).
// Last of 16 blocks computes the final loss (done-counter).
#define NT 1024
__global__ __launch_bounds__(NT) void k_topk4(
    const unsigned long long* __restrict__ lists, const unsigned int* __restrict__ cbase,
    const float* __restrict__ score1, const float* __restrict__ homo,
    float* __restrict__ out, float* __restrict__ gtbuf,
    unsigned long long* __restrict__ accum, unsigned int* __restrict__ dcnt) {
  int li = blockIdx.x;             // 0..15
  int src = li >> 3, b = li & 7;
  int tid = threadIdx.x;

  __shared__ unsigned long long sbuf[GCAP];
  __shared__ unsigned int s_bc[NBUCKET];
  __shared__ int s_bb;
  __shared__ unsigned int s_nsel;
  __shared__ float s_red[16];

  unsigned int N = cbase[li * CNT_STRIDE]; if (N > CAP) N = CAP;
  if (tid < NBUCKET) s_bc[tid] = cbase[(16 + li * NBUCKET + tid) * CNT_STRIDE];
  if (tid == 0) s_nsel = 0;
  __syncthreads();

  if (tid == 0) {
    unsigned int want = (N < TOPK) ? N : TOPK;
    int bb = NBUCKET;
    if (want > 0) {
      unsigned int cum = 0;
      for (int bk = NBUCKET - 1; bk >= 1; --bk) {
        cum += s_bc[bk];
        bb = bk;
        if (cum >= want) break;
      }
    }
    s_bb = bb;
  }
  __syncthreads();
  int bb = s_bb;

  // single gather scan with wave-aggregated LDS push
  const unsigned long long* list = lists + (size_t)li * CAP;
  int lane = tid & 63;
  for (unsigned int i = tid; i < N; i += NT) {
    unsigned long long k = list[i];
    float v = __uint_as_float((unsigned int)(k >> 32));
    bool pred = (vbucket(v) >= bb);
    unsigned long long mask = __ballot(pred);
    if (mask) {
      int leader = __ffsll((long long)mask) - 1;
      unsigned int cnt = (unsigned int)__popcll(mask);
      unsigned int bp = 0;
      if (lane == leader) bp = atomicAdd(&s_nsel, cnt);
      bp = __shfl(bp, leader, 64);
      if (pred) {
        unsigned int pos = bp + (unsigned int)__popcll(mask & ((1ULL << lane) - 1ULL));
        if (pos < GCAP) sbuf[pos] = k;
      }
    }
  }
  __syncthreads();
  unsigned int total = s_nsel; if (total > GCAP) total = GCAP;

  unsigned int S = 512; while (S < total) S <<= 1;
  for (unsigned int i = tid; i < S; i += NT)
    if (i >= total) sbuf[i] = 0ULL;
  __syncthreads();

  for (unsigned int k2 = 2; k2 <= S; k2 <<= 1) {
    for (unsigned int j = k2 >> 1; j > 0; j >>= 1) {
      for (unsigned int i = tid; i < S; i += NT) {
        unsigned int ixj = i ^ j;
        if (ixj > i) {
          bool desc = ((i & k2) == 0);
          unsigned long long a = sbuf[i], c = sbuf[ixj];
          bool sw = desc ? (a < c) : (a > c);
          if (sw) { sbuf[i] = c; sbuf[ixj] = a; }
        }
      }
      __syncthreads();
    }
  }

  if (src == 0) {
    for (int r = tid; r < TOPK; r += NT) {
      unsigned long long k = sbuf[r];
      unsigned int idx = (k == 0ULL) ? 0u : ~(unsigned int)(k & 0xFFFFFFFFULL);
      int yy = (int)(idx / NW), xx = (int)(idx % NW);
      out[1 + ((b * TOPK) + r) * 2 + 0] = (float)yy;
      out[1 + ((b * TOPK) + r) * 2 + 1] = (float)xx;
    }
  } else {
    const float* hm = homo + b * 9;
    float h0 = hm[0], h1 = hm[1], h2 = hm[2];
    float h3 = hm[3], h4 = hm[4], h5 = hm[5];
    float h6 = hm[6], h7 = hm[7], h8 = hm[8];
    unsigned int nw = (total < TOPK) ? total : TOPK;
    const float gw[5] = {G2, G1, G0, G1, G2};
    // scatter 5x5 taps (only this block touches image b)
    for (unsigned int r = tid; r < nw; r += NT) {
      unsigned long long k = sbuf[r];
      unsigned int idx = ~(unsigned int)(k & 0xFFFFFFFFULL);
      float val = __uint_as_float((unsigned int)(k >> 32));
      int y = (int)(idx / NW), x = (int)(idx % NW);
      #pragma unroll
      for (int dy = -2; dy <= 2; ++dy) {
        #pragma unroll
        for (int dx = -2; dx <= 2; ++dx) {
          float w = val * gw[dy + 2] * gw[dx + 2];
          atomicAdd(&gtbuf[b * NHW + (y + dy) * NW + (x + dx)], w);
        }
      }
    }
    __threadfence();
    __syncthreads();
    // dedup + correction: exactly-once via atomicExch (also restores gtbuf to 0)
    float term = 0.f;
    for (unsigned int r = tid; r < nw; r += NT) {
      unsigned long long k = sbuf[r];
      unsigned int idx = ~(unsigned int)(k & 0xFFFFFFFFULL);
      int y = (int)(idx / NW), x = (int)(idx % NW);
      #pragma unroll
      for (int dy = -2; dy <= 2; ++dy) {
        #pragma unroll
        for (int dx = -2; dx <= 2; ++dx) {
          int yy = y + dy, xx = x + dx;
          float gt = atomicExch(&gtbuf[b * NHW + yy * NW + xx], 0.f);
          if (gt != 0.f) {
            float s1 = bordered(score1, b, yy, xx);
            float v = vis_quad(h0, h1, h2, h3, h4, h5, h6, h7, h8, (float)xx, (float)yy);
            term += (gt - 2.f * s1) * gt * v;
          }
        }
      }
    }
    for (int m = 1; m < 64; m <<= 1) term += __shfl_xor(term, m, 64);
    if ((tid & 63) == 0) s_red[tid >> 6] = term;
    __syncthreads();
    if (tid == 0) {
      float bsum = 0.f;
      for (int w = 0; w < 16; ++w) bsum += s_red[w];
      long long fp = (long long)((double)bsum * 4294967296.0);
      atomicAdd(&accum[0], (unsigned long long)fp);
    }
  }

  // finisher: last block computes loss
  __syncthreads();
  if (tid == 0) {
    __threadfence();
    unsigned int old = atomicAdd(dcnt, 1u);
    if (old == 15u) {
      unsigned long long ts = atomicAdd(&accum[0], 0ULL);
      unsigned long long nv = atomicAdd(&accum[1], 0ULL);
      double tsd = (double)(long long)ts / 4294967296.0;
      out[0] = (float)(100.0 * tsd / (double)nv);
    }
  }
}

extern "C" void kernel_launch(void* const* d_in, const int* in_sizes, int n_in,
                              void* d_out, int out_size, void* d_ws, size_t ws_size,
                              hipStream_t stream) {
  const float* score1 = (const float*)d_in[0];
  const float* score2 = (const float*)d_in[1];
  const float* homo   = (const float*)d_in[2];
  float* out = (float*)d_out;

  // workspace layout
  float* gtbuf = (float*)d_ws;                                      // NBHW f32 (zeroed by k_nms4)
  unsigned long long* lists = (unsigned long long*)(gtbuf + NBHW);  // 16*CAP u64
  const int NCNT = (16 + 16 * NBUCKET) * CNT_STRIDE;
  unsigned int* cbase = (unsigned int*)(lists + (size_t)16 * CAP);  // counters (memset)
  unsigned long long* accum = (unsigned long long*)(cbase + NCNT);  // 2 u64
  unsigned int* dcnt = (unsigned int*)(accum + 2);                  // 1 u32

  size_t required = (size_t)NBHW * 4 + (size_t)16 * CAP * 8 + (size_t)NCNT * 4 + 64;
  if (ws_size < required) return;

  hipMemsetAsync(cbase, 0, (size_t)NCNT * 4 + 64, stream);

  dim3 gnms(NW / TW, NH / TH, 16);    // 10 x 16 x 16 = 2560 blocks
  k_nms4<<<gnms, 256, 0, stream>>>(score1, score2, homo, gtbuf, lists, cbase, accum);
  k_topk4<<<16, NT, 0, stream>>>(lists, cbase, score1, homo, out, gtbuf, accum, dcnt);
}

// Round 10
// 108.234 us; speedup vs baseline: 1.5219x; 1.3527x over previous
//
#include <hip/hip_runtime.h>

#define NB 8
#define NH 512
#define NW 640
#define NHW (NH*NW)
#define NBHW (NB*NHW)
#define TOPK 512
#define CAP 40960
#define PAD 8
#define CNT_STRIDE 64   // one counter per 256B cacheline
#define NBUCKET 32
#define GCAP 4096       // topk gather capacity (32 KB LDS)

// NMS tile geometry (block = 256 threads)
#define TW 64
#define TH 32
#define INH 36          // staged rows:  gy in [by*32-2, by*32+34)
#define INW 72          // staged cols (src0 covers -4..67, src1 covers -2..69)

// Gaussian taps exp(-2 d^2); |d|>=3 taps are <=1.52e-8 -> negligible, radius 2 used
#define G0 1.0f
#define G1 0.1353352832366127f
#define G2 3.3546262790251185e-4f

__device__ __forceinline__ float bordered(const float* __restrict__ img, int b, int y, int x) {
  if (y < PAD || y >= NH - PAD || x < PAD || x >= NW - PAD) return 0.f;
  return img[b * NHW + y * NW + x];
}

// Monotone (weakly increasing in val) bucket index, fine-grained near 1.0.
__device__ __forceinline__ int vbucket(float val) {
  int d = 0x3F800000 - (int)__float_as_uint(val);
  if (d <= 0) return NBUCKET - 1;
  int c = __clz(d);
  return c > 30 ? 30 : c;
}

__device__ __forceinline__ void corner(const float* __restrict__ img, float cx, float cy,
                                       float wgt, float& acc) {
  float valid = (cx >= 0.f && cx <= (float)(NW - 1) && cy >= 0.f && cy <= (float)(NH - 1)) ? 1.f : 0.f;
  float xc = fminf(fmaxf(cx, 0.f), (float)(NW - 1));
  float yc = fminf(fmaxf(cy, 0.f), (float)(NH - 1));
  int xi = (int)xc, yi = (int)yc;
  acc += wgt * img[yi * NW + xi] * valid;
}

// Division-free visibility: v=1 iff x2 in (-1,NW) and y2 in (-1,NH), x2=X/Z.
__device__ __forceinline__ float vis_quad(float h0, float h1, float h2, float h3, float h4,
                                          float h5, float h6, float h7, float h8,
                                          float xf, float yf) {
  float X = h0 * xf + h1 * yf + h2;
  float Y = h3 * xf + h4 * yf + h5;
  float Z = h6 * xf + h7 * yf + h8;
  bool ok = ((X + Z) * Z > 0.f) & ((640.f * Z - X) * Z > 0.f)
          & ((Y + Z) * Z > 0.f) & ((512.f * Z - Y) * Z > 0.f);
  return ok ? 1.f : 0.f;
}

// Fused warp + border-filter + 5x5 separable NMS + bucket counts (+dense loss, src0).
__global__ __launch_bounds__(256) void k_nms4(
    const float* __restrict__ score1, const float* __restrict__ score2,
    const float* __restrict__ homo,
    unsigned long long* __restrict__ lists, unsigned int* __restrict__ cbase,
    unsigned long long* __restrict__ accum) {
  int bx = blockIdx.x, by = blockIdx.y;
  int src = blockIdx.z >> 3, b = blockIdx.z & 7;
  int tid = threadIdx.x;

  __shared__ float in[INH][INW];       // 10.1 KB
  __shared__ float hmax[INH][TW];      // 9.0 KB
  __shared__ unsigned int s_cnt, s_base;
  __shared__ unsigned int s_bh[NBUCKET];
  __shared__ float s_wsum[4];
  __shared__ unsigned int s_wcnt[4];

  if (tid == 0) { s_cnt = 0; s_base = 0; }
  if (tid < NBUCKET) s_bh[tid] = 0;

  const float* hm = homo + b * 9;
  float h0 = hm[0], h1 = hm[1], h2 = hm[2];
  float h3 = hm[3], h4 = hm[4], h5 = hm[5];
  float h6 = hm[6], h7 = hm[7], h8 = hm[8];

  int y0t = by * TH, x0t = bx * TW;

  // Phase 1: stage tile into LDS (border-filtered values)
  if (src == 0) {
    // float4 staging from score1: 36 rows x 18 float4 (covers cols -4..67)
    for (int i = tid; i < INH * 18; i += 256) {
      int r = i / 18, c4 = i % 18;
      int gy = y0t + r - 2;
      int gx0 = x0t - 4 + c4 * 4;
      float4 v = make_float4(0.f, 0.f, 0.f, 0.f);
      if (gy >= PAD && gy < NH - PAD) {
        const float4* p = (const float4*)(score1 + (size_t)b * NHW + (size_t)gy * NW + gx0);
        float4 raw = *p;
        v.x = (gx0 + 0 >= PAD && gx0 + 0 < NW - PAD) ? raw.x : 0.f;
        v.y = (gx0 + 1 >= PAD && gx0 + 1 < NW - PAD) ? raw.y : 0.f;
        v.z = (gx0 + 2 >= PAD && gx0 + 2 < NW - PAD) ? raw.z : 0.f;
        v.w = (gx0 + 3 >= PAD && gx0 + 3 < NW - PAD) ? raw.w : 0.f;
      }
      *(float4*)&in[r][c4 * 4] = v;
    }
  } else {
    // warp staging: 36 rows x 68 cols (LDS cols 2..69)
    for (int i = tid; i < INH * 68; i += 256) {
      int r = i / 68, c = i % 68;
      int gy = y0t + r - 2, gx = x0t - 2 + c;
      float v = 0.f;
      if (gy >= PAD && gy < NH - PAD && gx >= PAD && gx < NW - PAD) {
        float xf = (float)gx, yf = (float)gy;
        float X = h0 * xf + h1 * yf + h2;
        float Y = h3 * xf + h4 * yf + h5;
        float Z = h6 * xf + h7 * yf + h8;
        float rz = __builtin_amdgcn_rcpf(Z);
        float x2 = X * rz, y2 = Y * rz;
        float x0 = floorf(x2), y0 = floorf(y2);
        float x1 = x0 + 1.f, y1 = y0 + 1.f;
        float wa = (x1 - x2) * (y1 - y2);
        float wb = (x2 - x0) * (y1 - y2);
        float wc = (x1 - x2) * (y2 - y0);
        float wd = (x2 - x0) * (y2 - y0);
        const float* img = score2 + b * NHW;
        float acc = 0.f;
        corner(img, x0, y0, wa, acc);
        corner(img, x1, y0, wb, acc);
        corner(img, x0, y1, wc, acc);
        corner(img, x1, y1, wd, acc);
        v = acc;
      }
      in[r][c + 2] = v;
    }
  }
  __syncthreads();

  // Phase 2: horizontal 5-max. hmax[r][c] = max(in[r][c+2 .. c+6])
  for (int i = tid; i < INH * TW; i += 256) {
    int r = i >> 6, c = i & 63;
    float m = fmaxf(fmaxf(fmaxf(in[r][c + 2], in[r][c + 3]), fmaxf(in[r][c + 4], in[r][c + 5])),
                    in[r][c + 6]);
    hmax[r][c] = m;
  }
  __syncthreads();

  // Phase 3: vertical 5-max + survivor detection; src0 also dense loss terms
  int nsv = 0;
  float sv[8];
  unsigned int si[8];
  float tsum = 0.f;
  int vcnt = 0;
  #pragma unroll
  for (int it = 0; it < (TH * TW) / 256; ++it) {
    int i = it * 256 + tid;
    int r = i >> 6, c = i & 63;
    int gy = y0t + r, gx = x0t + c;
    float val = in[r + 2][c + 4];
    if (src == 0) {
      float v = vis_quad(h0, h1, h2, h3, h4, h5, h6, h7, h8, (float)gx, (float)gy);
      tsum += val * val * v;
      vcnt += (v > 0.f) ? 1 : 0;
    }
    if (val > 0.f) {   // NMS_THRESH = 0
      float m = fmaxf(fmaxf(fmaxf(hmax[r][c], hmax[r + 1][c]), fmaxf(hmax[r + 2][c], hmax[r + 3][c])),
                      hmax[r + 4][c]);
      if (m == val) {
        sv[nsv] = val;
        si[nsv] = (unsigned int)(gy * NW + gx);
        ++nsv;
      }
    }
  }

  // Phase 4: LDS bookkeeping + wave reduce, then 2 barriers total
  unsigned int local = 0;
  if (nsv > 0) local = atomicAdd(&s_cnt, (unsigned int)nsv);
  #pragma unroll
  for (int j = 0; j < 8; ++j)
    if (j < nsv) atomicAdd(&s_bh[vbucket(sv[j])], 1u);

  if (src == 0) {
    for (int m = 1; m < 64; m <<= 1) {
      tsum += __shfl_xor(tsum, m, 64);
      vcnt += __shfl_xor(vcnt, m, 64);
    }
    if ((tid & 63) == 0) { s_wsum[tid >> 6] = tsum; s_wcnt[tid >> 6] = (unsigned int)vcnt; }
  }
  __syncthreads();

  int li = src * NB + b;
  if (tid == 0) {
    if (s_cnt > 0) s_base = atomicAdd(&cbase[li * CNT_STRIDE], s_cnt);
    if (src == 0) {
      float ts = s_wsum[0] + s_wsum[1] + s_wsum[2] + s_wsum[3];
      unsigned int vc = s_wcnt[0] + s_wcnt[1] + s_wcnt[2] + s_wcnt[3];
      long long fp = (long long)((double)ts * 4294967296.0);
      atomicAdd(&accum[0], (unsigned long long)fp);
      atomicAdd(&accum[1], (unsigned long long)vc);
    }
  }
  if (tid < NBUCKET && s_bh[tid] > 0)
    atomicAdd(&cbase[(16 + li * NBUCKET + tid) * CNT_STRIDE], s_bh[tid]);
  __syncthreads();

  unsigned int base = s_base;
  #pragma unroll
  for (int j = 0; j < 8; ++j) {
    if (j < nsv) {
      unsigned int pos = base + local + (unsigned int)j;
      if (pos < CAP) {
        unsigned long long key = ((unsigned long long)__float_as_uint(sv[j]) << 32)
                               | (unsigned long long)(~si[j]);
        lists[(size_t)li * CAP + pos] = key;
      }
    }
  }
}

// Exact top-512 per (source,image): bucket counts -> one gather scan -> bitonic sort.
// src0 -> kp1 out. src1 -> winners re-sorted by pixel idx asc, written compact.
#define NT 1024
__global__ __launch_bounds__(NT) void k_topk5(
    const unsigned long long* __restrict__ lists, const unsigned int* __restrict__ cbase,
    float* __restrict__ out, unsigned long long* __restrict__ winners,
    unsigned int* __restrict__ wcnt) {
  int li = blockIdx.x;             // 0..15
  int src = li >> 3, b = li & 7;
  int tid = threadIdx.x;

  __shared__ unsigned long long sbuf[GCAP];
  __shared__ unsigned int s_bc[NBUCKET];
  __shared__ int s_bb;
  __shared__ unsigned int s_nsel;

  unsigned int N = cbase[li * CNT_STRIDE]; if (N > CAP) N = CAP;
  if (tid < NBUCKET) s_bc[tid] = cbase[(16 + li * NBUCKET + tid) * CNT_STRIDE];
  if (tid == 0) s_nsel = 0;
  __syncthreads();

  if (tid == 0) {
    unsigned int want = (N < TOPK) ? N : TOPK;
    int bb = NBUCKET;
    if (want > 0) {
      unsigned int cum = 0;
      for (int bk = NBUCKET - 1; bk >= 1; --bk) {
        cum += s_bc[bk];
        bb = bk;
        if (cum >= want) break;
      }
    }
    s_bb = bb;
  }
  __syncthreads();
  int bb = s_bb;

  // single gather scan with wave-aggregated LDS push
  const unsigned long long* list = lists + (size_t)li * CAP;
  int lane = tid & 63;
  for (unsigned int i = tid; i < N; i += NT) {
    unsigned long long k = list[i];
    float v = __uint_as_float((unsigned int)(k >> 32));
    bool pred = (vbucket(v) >= bb);
    unsigned long long mask = __ballot(pred);
    if (mask) {
      int leader = __ffsll((long long)mask) - 1;
      unsigned int cnt = (unsigned int)__popcll(mask);
      unsigned int bp = 0;
      if (lane == leader) bp = atomicAdd(&s_nsel, cnt);
      bp = __shfl(bp, leader, 64);
      if (pred) {
        unsigned int pos = bp + (unsigned int)__popcll(mask & ((1ULL << lane) - 1ULL));
        if (pos < GCAP) sbuf[pos] = k;
      }
    }
  }
  __syncthreads();
  unsigned int total = s_nsel; if (total > GCAP) total = GCAP;

  unsigned int S = 512; while (S < total) S <<= 1;
  for (unsigned int i = tid; i < S; i += NT)
    if (i >= total) sbuf[i] = 0ULL;
  __syncthreads();

  // sort descending by full key (val desc, idx asc)
  for (unsigned int k2 = 2; k2 <= S; k2 <<= 1) {
    for (unsigned int j = k2 >> 1; j > 0; j >>= 1) {
      for (unsigned int i = tid; i < S; i += NT) {
        unsigned int ixj = i ^ j;
        if (ixj > i) {
          bool desc = ((i & k2) == 0);
          unsigned long long a = sbuf[i], c = sbuf[ixj];
          bool sw = desc ? (a < c) : (a > c);
          if (sw) { sbuf[i] = c; sbuf[ixj] = a; }
        }
      }
      __syncthreads();
    }
  }

  if (src == 0) {
    for (int r = tid; r < TOPK; r += NT) {
      unsigned long long k = sbuf[r];
      unsigned int idx = (k == 0ULL) ? 0u : ~(unsigned int)(k & 0xFFFFFFFFULL);
      int yy = (int)(idx / NW), xx = (int)(idx % NW);
      out[1 + ((b * TOPK) + r) * 2 + 0] = (float)yy;
      out[1 + ((b * TOPK) + r) * 2 + 1] = (float)xx;
    }
  } else {
    unsigned int nw = (total < TOPK) ? total : TOPK;
    // re-key first 512 slots as (idx<<32)|valbits; pad with all-ones
    for (int r = tid; r < TOPK; r += NT) {
      unsigned long long k = sbuf[r];
      unsigned long long nk = ~0ULL;
      if (r < (int)nw && k != 0ULL) {
        unsigned int idx = ~(unsigned int)(k & 0xFFFFFFFFULL);
        nk = ((unsigned long long)idx << 32) | (k >> 32);
      }
      sbuf[r] = nk;
    }
    __syncthreads();
    // bitonic ascending sort of 512 (idx asc; idx unique)
    for (unsigned int k2 = 2; k2 <= TOPK; k2 <<= 1) {
      for (unsigned int j = k2 >> 1; j > 0; j >>= 1) {
        for (unsigned int i = tid; i < TOPK; i += NT) {
          unsigned int ixj = i ^ j;
          if (ixj > i) {
            bool asc = ((i & k2) == 0);
            unsigned long long a = sbuf[i], c = sbuf[ixj];
            bool sw = asc ? (a > c) : (a < c);
            if (sw) { sbuf[i] = c; sbuf[ixj] = a; }
          }
        }
        __syncthreads();
      }
    }
    for (int r = tid; r < TOPK; r += NT) winners[b * TOPK + r] = sbuf[r];
    if (tid == 0) wcnt[b] = nw;
  }
}

// Sparse gt + correction, gather-based (no gtbuf):
// task = (winner i, tap k). Pixel p = pos_i + offset(k). Contributors found by
// binary search over winners sorted by idx; min-idx contributor owns p.
// Fully deterministic (fixed scan order; integer accumulation only).
__global__ __launch_bounds__(256) void k_gt(
    const float* __restrict__ score1, const float* __restrict__ homo,
    const unsigned long long* __restrict__ winners, const unsigned int* __restrict__ wcnt,
    unsigned long long* __restrict__ accum, unsigned int* __restrict__ dcnt,
    float* __restrict__ out) {
  int b = blockIdx.y;
  int tid = threadIdx.x;
  __shared__ unsigned long long w[TOPK];
  __shared__ float s_red[4];

  unsigned int nw = wcnt[b];
  for (int i = tid; i < TOPK; i += 256)
    w[i] = (i < (int)nw) ? winners[b * TOPK + i] : ~0ULL;
  __syncthreads();

  const float* hm = homo + b * 9;
  float h0 = hm[0], h1 = hm[1], h2 = hm[2];
  float h3 = hm[3], h4 = hm[4], h5 = hm[5];
  float h6 = hm[6], h7 = hm[7], h8 = hm[8];

  const float gw5[5] = {G2, G1, G0, G1, G2};
  unsigned int r = blockIdx.x * 256u + (unsigned int)tid;  // task id in image
  unsigned int i = r / 25u, k = r % 25u;
  float term = 0.f;
  if (i < nw) {
    unsigned long long wk = w[i];
    unsigned int idx = (unsigned int)(wk >> 32);
    int y = (int)(idx / NW), x = (int)(idx % NW);
    int py = y + (int)(k / 5u) - 2, px = x + (int)(k % 5u) - 2;

    float gt = 0.f;
    unsigned int firstIdx = 0xFFFFFFFFu;
    #pragma unroll
    for (int dr = -2; dr <= 2; ++dr) {
      int ry = py + dr;
      unsigned int lo = (unsigned int)(ry * NW + px - 2);
      unsigned int hi = (unsigned int)(ry * NW + px + 2);
      unsigned long long lokey = ((unsigned long long)lo << 32);
      // lower bound: first j with w[j] >= lokey
      int a = 0, e = TOPK;
      while (a < e) { int m = (a + e) >> 1; if (w[m] < lokey) a = m + 1; else e = m; }
      for (int j = a; j < TOPK; ++j) {
        unsigned long long c = w[j];
        unsigned int cidx = (unsigned int)(c >> 32);
        if (cidx > hi) break;
        float cval = __uint_as_float((unsigned int)(c & 0xFFFFFFFFULL));
        int cx = (int)(cidx % NW);
        gt += cval * gw5[dr + 2] * gw5[cx - px + 2];
        if (firstIdx == 0xFFFFFFFFu) firstIdx = cidx;
      }
    }
    if (firstIdx == idx) {   // this winner owns pixel p
      float s1 = bordered(score1, b, py, px);
      float v = vis_quad(h0, h1, h2, h3, h4, h5, h6, h7, h8, (float)px, (float)py);
      term = (gt - 2.f * s1) * gt * v;
    }
  }

  for (int m = 1; m < 64; m <<= 1) term += __shfl_xor(term, m, 64);
  if ((tid & 63) == 0) s_red[tid >> 6] = term;
  __syncthreads();
  if (tid == 0) {
    float bsum = s_red[0] + s_red[1] + s_red[2] + s_red[3];
    long long fp = (long long)((double)bsum * 4294967296.0);
    atomicAdd(&accum[0], (unsigned long long)fp);
    __threadfence();
    unsigned int old = atomicAdd(dcnt, 1u);
    if (old == gridDim.x * gridDim.y - 1u) {
      unsigned long long ts = atomicAdd(&accum[0], 0ULL);
      unsigned long long nv = atomicAdd(&accum[1], 0ULL);
      double tsd = (double)(long long)ts / 4294967296.0;
      out[0] = (float)(100.0 * tsd / (double)nv);
    }
  }
}

extern "C" void kernel_launch(void* const* d_in, const int* in_sizes, int n_in,
                              void* d_out, int out_size, void* d_ws, size_t ws_size,
                              hipStream_t stream) {
  const float* score1 = (const float*)d_in[0];
  const float* score2 = (const float*)d_in[1];
  const float* homo   = (const float*)d_in[2];
  float* out = (float*)d_out;

  // workspace layout
  unsigned long long* lists = (unsigned long long*)d_ws;            // 16*CAP u64
  const int NCNT = (16 + 16 * NBUCKET) * CNT_STRIDE;
  unsigned int* cbase = (unsigned int*)(lists + (size_t)16 * CAP);  // counters (memset)
  unsigned int* tail = cbase + NCNT;                                // 16 u32 (memset)
  unsigned long long* accum = (unsigned long long*)tail;            // 2 u64
  unsigned int* dcnt = tail + 4;                                    // 1 u32
  unsigned int* wcnt = tail + 8;                                    // 8 u32
  unsigned long long* winners = (unsigned long long*)(tail + 16);   // 8*512 u64

  size_t required = (size_t)16 * CAP * 8 + (size_t)NCNT * 4 + 64 + (size_t)NB * TOPK * 8;
  if (ws_size < required) return;

  hipMemsetAsync(cbase, 0, (size_t)NCNT * 4 + 64, stream);

  dim3 gnms(NW / TW, NH / TH, 16);    // 10 x 16 x 16 = 2560 blocks
  k_nms4<<<gnms, 256, 0, stream>>>(score1, score2, homo, lists, cbase, accum);
  k_topk5<<<16, NT, 0, stream>>>(lists, cbase, out, winners, wcnt);
  dim3 ggt((TOPK * 25) / 256, NB);    // 50 x 8 = 400 blocks
  k_gt<<<ggt, 256, 0, stream>>>(score1, homo, winners, wcnt, accum, dcnt, out);
}